// Round 7
// baseline (2998.616 us; speedup 1.0000x reference)
//
#include <hip/hip_runtime.h>
#include <cstdint>
#include <cstddef>

// BottomUpNet: N=8192 rows independent; K=16 sequential steps.
// R18: arithmetic post-mortem of R11-R17 (all ~44us, MfmaUtil ~32%):
// per-CU per K-tile, MFMA = 1024 cyc but LDS reads = 1152 cyc (8 waves x
// 12 ds_read_b128 x 12cyc) and the phase barriers SERIALIZE them. Fix:
//  (1) wave tile 64x64 -> 128x64 (4 waves, acc[4][2]): MFMA/ds_read ratio
//      1.33 -> 2.0; LDS reads 768 cyc < MFMA 1024 -> hideable.
//  (2) register read-ahead (AITER s02): ds_read tile t+1's frags BEFORE
//      MFMA(t) cluster; LDS services them under the 1024-cyc MFMA; the
//      lgkm drain next tile is free. ONE barrier per K-tile.
//  (3) 4 LDS buffers (128KB split / 96KB h): STAGE(t+2) overwrites buf
//      t-2, provably past a collective barrier after its last reader.
//      vmcnt(8)/(6) = one tile in flight, never 0 mid-loop.
//  (4) launch_bounds(256,1): 1 wave/SIMD, 512-VGPR budget (acc 128 +
//      2x64 frag VGPRs, no spill). Low occupancy EXPECTED (R14 lesson).
// MFMA chain per output element unchanged (kh asc, lo->hi):
// absmax must stay exactly 1.192093e-07 — revert if it moves.

typedef _Float16 f16x8 __attribute__((ext_vector_type(8)));
typedef float f32x16 __attribute__((ext_vector_type(16)));

#define MF(d, a, b) d = __builtin_amdgcn_mfma_f32_32x32x16_f16(a, b, d, 0, 0, 0)
#define CFENCE() asm volatile("" ::: "memory")

__device__ __forceinline__ void gload16(const void* g, void* l) {
  // async global->LDS, 16B/lane, LDS dest = wave-uniform base + lane*16
  __builtin_amdgcn_global_load_lds(
      (__attribute__((address_space(1))) void*)const_cast<void*>(g),
      (__attribute__((address_space(3))) void*)l,
      16, 0, 0);
}

// ---- m-GEMM: C = relu(A@B^T + bias); A fp16 hi; B hi/lo fp16 (2 MFMAs).
// Tile 256x128, BK=32, 4 waves (128x64 each), 4-buffer read-ahead pipeline.
__global__ __launch_bounds__(256, 1)
void gemm_split_kernel(const _Float16* __restrict__ AH0, int ldA0,
                       const _Float16* __restrict__ AH1, int ldA1,
                       int kcut, int Ktot,
                       const _Float16* __restrict__ BH, const _Float16* __restrict__ BL,
                       const float* __restrict__ bias,
                       _Float16* __restrict__ CH, int ldC)
{
  __shared__ _Float16 sA[4][256 * 32];   // 64 KB
  __shared__ _Float16 sB[4][128 * 32];   // 32 KB
  __shared__ _Float16 sL[4][128 * 32];   // 32 KB

  const int lane = threadIdx.x & 63;
  const int wave = threadIdx.x >> 6;               // 0..3
  const int wm = (wave >> 1) * 128, wn = (wave & 1) * 64;
  const int mBase = blockIdx.x * 256, nBase = blockIdx.y * 128;

  // paired-row staging layout (R13-verified)
  const int lr  = 2 * (lane >> 3) + ((lane >> 2) & 1);
  const int lcs = (((lane & 3) ^ ((lane >> 3) & 3)) * 8);

  const int l31 = lane & 31, l5 = lane >> 5;
  const int rowoff = (l31 >> 1) * 64 + (l31 & 1) * 32;
  const int fswz = (l31 >> 1) & 3;
  const int ko0 = (l5 ^ fswz) * 8;
  const int ko1 = ((2 + l5) ^ fswz) * 8;

  // staging sources: A chunks wave+4q (q=0..3), B/L chunks wave+4q (q=0..1)
  const _Float16 *aS0[4], *aS1[4], *bS[2], *lS[2];
#pragma unroll
  for (int q = 0; q < 4; ++q) {
    const int row = mBase + (wave + q * 4) * 16 + lr;
    aS0[q] = AH0 + (size_t)row * ldA0 + lcs;
    aS1[q] = AH1 + (size_t)row * ldA1 + lcs;
  }
#pragma unroll
  for (int q = 0; q < 2; ++q) {
    const int row = nBase + (wave + q * 4) * 16 + lr;
    bS[q] = BH + (size_t)row * Ktot + lcs;
    lS[q] = BL + (size_t)row * Ktot + lcs;
  }

  f32x16 acc[4][2];
#pragma unroll
  for (int i = 0; i < 4; ++i)
#pragma unroll
    for (int j = 0; j < 2; ++j) acc[i][j] = (f32x16)0.0f;

  _Float16 *uA0 = &sA[0][0], *uA1 = &sA[1][0], *uA2 = &sA[2][0], *uA3 = &sA[3][0];
  _Float16 *uB0 = &sB[0][0], *uB1 = &sB[1][0], *uB2 = &sB[2][0], *uB3 = &sB[3][0];
  _Float16 *uL0 = &sL[0][0], *uL1 = &sL[1][0], *uL2 = &sL[2][0], *uL3 = &sL[3][0];

  auto STAGE = [&](_Float16* dA, _Float16* dB, _Float16* dL, int kt) {  // 8 loads
    const bool lo = kt < kcut;
    const int kl = lo ? kt : kt - kcut;
#pragma unroll
    for (int q = 0; q < 4; ++q)
      gload16((lo ? aS0[q] : aS1[q]) + kl, dA + (wave + q * 4) * 512);
#pragma unroll
    for (int q = 0; q < 2; ++q) {
      gload16(bS[q] + kt, dB + (wave + q * 4) * 512);
      gload16(lS[q] + kt, dL + (wave + q * 4) * 512);
    }
  };

  auto DSREAD = [&](const _Float16* pA, const _Float16* pB, const _Float16* pL,
                    f16x8 (&a)[4][2], f16x8 (&b)[2][2], f16x8 (&c)[2][2]) {  // 16 b128
#pragma unroll
    for (int i = 0; i < 4; ++i) {
      const int base = (wm + i * 32) * 32 + rowoff;
      a[i][0] = *(const f16x8*)(pA + base + ko0);
      a[i][1] = *(const f16x8*)(pA + base + ko1);
    }
#pragma unroll
    for (int j = 0; j < 2; ++j) {
      const int base = (wn + j * 32) * 32 + rowoff;
      b[j][0] = *(const f16x8*)(pB + base + ko0);
      b[j][1] = *(const f16x8*)(pB + base + ko1);
      c[j][0] = *(const f16x8*)(pL + base + ko0);
      c[j][1] = *(const f16x8*)(pL + base + ko1);
    }
  };

  auto MFMACL = [&](f16x8 (&a)[4][2], f16x8 (&b)[2][2], f16x8 (&c)[2][2]) {  // 32 MFMA
#pragma unroll
    for (int kh = 0; kh < 2; ++kh) {
#pragma unroll
      for (int i = 0; i < 4; ++i)
#pragma unroll
        for (int j = 0; j < 2; ++j) MF(acc[i][j], a[i][kh], c[j][kh]);   // lo block
#pragma unroll
      for (int i = 0; i < 4; ++i)
#pragma unroll
        for (int j = 0; j < 2; ++j) MF(acc[i][j], a[i][kh], b[j][kh]);   // hi block
    }
  };

  f16x8 aX[4][2], bX[2][2], cX[2][2];
  f16x8 aY[4][2], bY[2][2], cY[2][2];

  const int NT = Ktot >> 5;                    // 32 or 34 (even)
  STAGE(uA0, uB0, uL0, 0);
  STAGE(uA1, uB1, uL1, 32);
  asm volatile("s_waitcnt vmcnt(8)" ::: "memory");  // tile0 landed
  __builtin_amdgcn_s_barrier();
  CFENCE();
  DSREAD(uA0, uB0, uL0, aX, bX, cX);

  for (int t = 0; t < NT; t += 2) {
    // ---- even: compute X(t); read-ahead Y(t+1); stage(t+2) -> u2
    {
      const bool s2 = (t + 2) < NT;
      if (s2) STAGE(uA2, uB2, uL2, (t + 2) * 32);
      if (s2) asm volatile("s_waitcnt vmcnt(8)" ::: "memory");
      else    asm volatile("s_waitcnt vmcnt(0)" ::: "memory");
      __builtin_amdgcn_s_barrier();
      CFENCE();
      asm volatile("s_waitcnt lgkmcnt(0)" ::: "memory");  // X-reads done (free)
      DSREAD(uA1, uB1, uL1, aY, bY, cY);                  // t+1 always < NT
      __builtin_amdgcn_sched_barrier(0);
      __builtin_amdgcn_s_setprio(1);
      MFMACL(aX, bX, cX);
      __builtin_amdgcn_s_setprio(0);
    }
    // ---- odd: compute Y(t+1); read-ahead X(t+2); stage(t+3) -> u3
    {
      const bool s2 = (t + 3) < NT;
      const bool r2 = (t + 2) < NT;
      if (s2) STAGE(uA3, uB3, uL3, (t + 3) * 32);
      if (s2)      asm volatile("s_waitcnt vmcnt(8)" ::: "memory");
      else if (r2) asm volatile("s_waitcnt vmcnt(0)" ::: "memory");
      __builtin_amdgcn_s_barrier();
      CFENCE();
      asm volatile("s_waitcnt lgkmcnt(0)" ::: "memory");  // Y-reads done
      if (r2) DSREAD(uA2, uB2, uL2, aX, bX, cX);
      __builtin_amdgcn_sched_barrier(0);
      __builtin_amdgcn_s_setprio(1);
      MFMACL(aY, bY, cY);
      __builtin_amdgcn_s_setprio(0);
    }
    { _Float16* tp;
      tp = uA0; uA0 = uA2; uA2 = tp;  tp = uA1; uA1 = uA3; uA3 = tp;
      tp = uB0; uB0 = uB2; uB2 = tp;  tp = uB1; uB1 = uB3; uB3 = tp;
      tp = uL0; uL0 = uL2; uL2 = tp;  tp = uL1; uL1 = uL3; uL3 = tp; }
  }

  float bv[2];
#pragma unroll
  for (int j = 0; j < 2; ++j) bv[j] = bias[nBase + wn + j * 32 + l31];
#pragma unroll
  for (int i = 0; i < 4; ++i)
#pragma unroll
    for (int j = 0; j < 2; ++j)
#pragma unroll
      for (int r = 0; r < 16; ++r) {
        const int row = mBase + wm + i * 32 + (r & 3) + 8 * (r >> 2) + 4 * l5;
        const int col = nBase + wn + j * 32 + l31;
        float v = fmaxf(acc[i][j][r] + bv[j], 0.0f);
        CH[(size_t)row * ldC + col] = (_Float16)v;
      }
}

// ---- fp16 GEMM (hi-only, 1 MFMA): C = relu(A@B^T + bias) fp16 out,
// or fused-pred mode (sacc != null): sacc[row] += sum_col relu(.)*w3[col]
__global__ __launch_bounds__(256, 1)
void gemm_h_kernel(const _Float16* __restrict__ A0, int ldA0,
                   const _Float16* __restrict__ A1, int ldA1,
                   int kcut, int Ktot,
                   const _Float16* __restrict__ B,
                   const float* __restrict__ bias,
                   _Float16* __restrict__ C, int ldC,
                   const float* __restrict__ w3, float* __restrict__ sacc)
{
  __shared__ _Float16 sA[4][256 * 32];   // 64 KB
  __shared__ _Float16 sB[4][128 * 32];   // 32 KB

  const int lane = threadIdx.x & 63;
  const int wave = threadIdx.x >> 6;
  const int wm = (wave >> 1) * 128, wn = (wave & 1) * 64;
  const int mBase = blockIdx.x * 256, nBase = blockIdx.y * 128;

  const int lr  = 2 * (lane >> 3) + ((lane >> 2) & 1);
  const int lcs = (((lane & 3) ^ ((lane >> 3) & 3)) * 8);

  const int l31 = lane & 31, l5 = lane >> 5;
  const int rowoff = (l31 >> 1) * 64 + (l31 & 1) * 32;
  const int fswz = (l31 >> 1) & 3;
  const int ko0 = (l5 ^ fswz) * 8;
  const int ko1 = ((2 + l5) ^ fswz) * 8;

  const _Float16 *aS0[4], *aS1[4], *bS[2];
#pragma unroll
  for (int q = 0; q < 4; ++q) {
    const int row = mBase + (wave + q * 4) * 16 + lr;
    aS0[q] = A0 + (size_t)row * ldA0 + lcs;
    aS1[q] = A1 + (size_t)row * ldA1 + lcs;
  }
#pragma unroll
  for (int q = 0; q < 2; ++q) {
    const int row = nBase + (wave + q * 4) * 16 + lr;
    bS[q] = B + (size_t)row * Ktot + lcs;
  }

  f32x16 acc[4][2];
#pragma unroll
  for (int i = 0; i < 4; ++i)
#pragma unroll
    for (int j = 0; j < 2; ++j) acc[i][j] = (f32x16)0.0f;

  _Float16 *uA0 = &sA[0][0], *uA1 = &sA[1][0], *uA2 = &sA[2][0], *uA3 = &sA[3][0];
  _Float16 *uB0 = &sB[0][0], *uB1 = &sB[1][0], *uB2 = &sB[2][0], *uB3 = &sB[3][0];

  auto STAGE = [&](_Float16* dA, _Float16* dB, int kt) {   // 6 loads
    const bool lo = kt < kcut;
    const int kl = lo ? kt : kt - kcut;
#pragma unroll
    for (int q = 0; q < 4; ++q)
      gload16((lo ? aS0[q] : aS1[q]) + kl, dA + (wave + q * 4) * 512);
#pragma unroll
    for (int q = 0; q < 2; ++q)
      gload16(bS[q] + kt, dB + (wave + q * 4) * 512);
  };

  auto DSREAD = [&](const _Float16* pA, const _Float16* pB,
                    f16x8 (&a)[4][2], f16x8 (&b)[2][2]) {  // 12 b128
#pragma unroll
    for (int i = 0; i < 4; ++i) {
      const int base = (wm + i * 32) * 32 + rowoff;
      a[i][0] = *(const f16x8*)(pA + base + ko0);
      a[i][1] = *(const f16x8*)(pA + base + ko1);
    }
#pragma unroll
    for (int j = 0; j < 2; ++j) {
      const int base = (wn + j * 32) * 32 + rowoff;
      b[j][0] = *(const f16x8*)(pB + base + ko0);
      b[j][1] = *(const f16x8*)(pB + base + ko1);
    }
  };

  auto MFMACL = [&](f16x8 (&a)[4][2], f16x8 (&b)[2][2]) {  // 16 MFMA
#pragma unroll
    for (int kh = 0; kh < 2; ++kh)
#pragma unroll
      for (int i = 0; i < 4; ++i)
#pragma unroll
        for (int j = 0; j < 2; ++j) MF(acc[i][j], a[i][kh], b[j][kh]);
  };

  f16x8 aX[4][2], bX[2][2];
  f16x8 aY[4][2], bY[2][2];

  const int NT = Ktot >> 5;
  STAGE(uA0, uB0, 0);
  STAGE(uA1, uB1, 32);
  asm volatile("s_waitcnt vmcnt(6)" ::: "memory");
  __builtin_amdgcn_s_barrier();
  CFENCE();
  DSREAD(uA0, uB0, aX, bX);

  for (int t = 0; t < NT; t += 2) {
    {
      const bool s2 = (t + 2) < NT;
      if (s2) STAGE(uA2, uB2, (t + 2) * 32);
      if (s2) asm volatile("s_waitcnt vmcnt(6)" ::: "memory");
      else    asm volatile("s_waitcnt vmcnt(0)" ::: "memory");
      __builtin_amdgcn_s_barrier();
      CFENCE();
      asm volatile("s_waitcnt lgkmcnt(0)" ::: "memory");
      DSREAD(uA1, uB1, aY, bY);
      __builtin_amdgcn_sched_barrier(0);
      __builtin_amdgcn_s_setprio(1);
      MFMACL(aX, bX);
      __builtin_amdgcn_s_setprio(0);
    }
    {
      const bool s2 = (t + 3) < NT;
      const bool r2 = (t + 2) < NT;
      if (s2) STAGE(uA3, uB3, (t + 3) * 32);
      if (s2)      asm volatile("s_waitcnt vmcnt(6)" ::: "memory");
      else if (r2) asm volatile("s_waitcnt vmcnt(0)" ::: "memory");
      __builtin_amdgcn_s_barrier();
      CFENCE();
      asm volatile("s_waitcnt lgkmcnt(0)" ::: "memory");
      if (r2) DSREAD(uA2, uB2, aX, bX);
      __builtin_amdgcn_sched_barrier(0);
      __builtin_amdgcn_s_setprio(1);
      MFMACL(aY, bY);
      __builtin_amdgcn_s_setprio(0);
    }
    { _Float16* tp;
      tp = uA0; uA0 = uA2; uA2 = tp;  tp = uA1; uA1 = uA3; uA3 = tp;
      tp = uB0; uB0 = uB2; uB2 = tp;  tp = uB1; uB1 = uB3; uB3 = tp; }
  }

  float bv[2], w3v[2];
#pragma unroll
  for (int j = 0; j < 2; ++j) {
    const int col = nBase + wn + j * 32 + l31;
    bv[j] = bias[col];
    w3v[j] = sacc ? w3[col] : 0.0f;
  }

  if (sacc) {
    // fused pred partial: one value per C/D row, reduced over the 32 col-lanes
#pragma unroll
    for (int i = 0; i < 4; ++i)
#pragma unroll
      for (int r = 0; r < 16; ++r) {
        float pr = 0.0f;
#pragma unroll
        for (int j = 0; j < 2; ++j)
          pr += fmaxf(acc[i][j][r] + bv[j], 0.0f) * w3v[j];
        pr += __shfl_xor(pr, 1);
        pr += __shfl_xor(pr, 2);
        pr += __shfl_xor(pr, 4);
        pr += __shfl_xor(pr, 8);
        pr += __shfl_xor(pr, 16);
        if (l31 == 0)
          atomicAdd(&sacc[mBase + wm + i * 32 + (r & 3) + 8 * (r >> 2) + 4 * l5], pr);
      }
  } else {
#pragma unroll
    for (int i = 0; i < 4; ++i)
#pragma unroll
      for (int j = 0; j < 2; ++j)
#pragma unroll
        for (int r = 0; r < 16; ++r) {
          const int row = mBase + wm + i * 32 + (r & 3) + 8 * (r >> 2) + 4 * l5;
          const int col = nBase + wn + j * 32 + l31;
          float v = fmaxf(acc[i][j][r] + bv[j], 0.0f);
          C[(size_t)row * ldC + col] = (_Float16)v;
        }
  }
}

// W (K x N fp32, row-major) -> out (N x K fp16 hi[/lo]), i.e. transposed
__global__ void wconv_kernel(const float* __restrict__ W, int K, int N,
                             _Float16* __restrict__ oH, _Float16* __restrict__ oL) {
  int idx = blockIdx.x * 256 + threadIdx.x;   // idx = n*K + k (output-coalesced)
  if (idx >= K * N) return;
  int n = idx / K, k = idx - n * K;
  float v = W[(size_t)k * N + n];
  _Float16 h = (_Float16)v;
  oH[idx] = h;
  if (oL) oL[idx] = (_Float16)(v - (float)h);
}

__global__ void init_summary_kernel(const float* __restrict__ agg,
                                    _Float16* __restrict__ sH,
                                    float* __restrict__ sacc) {
  int idx = blockIdx.x * 256 + threadIdx.x;   // 8192*1024
  sH[idx] = (_Float16)agg[idx & 1023];
  if (idx < 8192) sacc[idx] = 0.0f;
}

// towers [n][k][f] fp32 -> towAll [k][n][f] fp16 hi (all 16 slices)
__global__ void tow_conv_all_kernel(const float* __restrict__ towers,
                                    _Float16* __restrict__ oH) {
  size_t idx = (size_t)blockIdx.x * 256 + threadIdx.x;  // (k*8192+n)*64+f
  int f = idx & 63;
  int n = (int)((idx >> 6) & 8191);
  int k = (int)(idx >> 19);
  oH[idx] = (_Float16)towers[((size_t)n * 16 + k) * 64 + f];
}

// pred = sigmoid(sacc + Ob3); out *= pred; re-zero sacc for next step
__global__ void pred_final_kernel(float* __restrict__ sacc, const float* __restrict__ b3,
                                  float* __restrict__ out, int step) {
  int row = blockIdx.x * 256 + threadIdx.x;   // 8192
  float p = 1.0f / (1.0f + expf(-(sacc[row] + b3[0])));
  out[row] = (step == 0) ? p : out[row] * p;
  sacc[row] = 0.0f;
}

extern "C" void kernel_launch(void* const* d_in, const int* in_sizes, int n_in,
                              void* d_out, int out_size, void* d_ws, size_t ws_size,
                              hipStream_t stream) {
  const float* towers = (const float*)d_in[0];
  const float* agg    = (const float*)d_in[1];
  const float* MW1 = (const float*)d_in[2];
  const float* Mb1 = (const float*)d_in[3];
  const float* MW2 = (const float*)d_in[4];
  const float* Mb2 = (const float*)d_in[5];
  const float* MW3 = (const float*)d_in[6];
  const float* Mb3 = (const float*)d_in[7];
  const float* OW1 = (const float*)d_in[8];
  const float* Ob1 = (const float*)d_in[9];
  const float* OW2 = (const float*)d_in[10];
  const float* Ob2 = (const float*)d_in[11];
  const float* OW3 = (const float*)d_in[12];
  const float* Ob3 = (const float*)d_in[13];
  float* out = (float*)d_out;

  // ws layout (~110 MiB)
  _Float16* p = (_Float16*)d_ws;
  _Float16* MW1tH = p; p += (size_t)1024 * 1088;
  _Float16* MW1tL = p; p += (size_t)1024 * 1088;
  _Float16* OW1tH = p; p += (size_t)1024 * 1088;
  _Float16* MW2tH = p; p += (size_t)1024 * 1024;
  _Float16* MW2tL = p; p += (size_t)1024 * 1024;
  _Float16* OW2tH = p; p += (size_t)1024 * 1024;
  _Float16* MW3tH = p; p += (size_t)1024 * 1024;
  _Float16* MW3tL = p; p += (size_t)1024 * 1024;
  _Float16* sumH  = p; p += (size_t)8192 * 1024;
  _Float16* m1H   = p; p += (size_t)8192 * 1024;
  _Float16* h1    = p; p += (size_t)8192 * 1024;
  _Float16* m2H   = p; p += (size_t)8192 * 1024;
  _Float16* towAllH = p; p += (size_t)16 * 8192 * 64;
  float* sacc = (float*)p;

  // per-call setup: transpose+split weights, convert towers, init summary
  {
    int tot = 1088 * 1024;
    wconv_kernel<<<dim3((tot + 255) / 256), dim3(256), 0, stream>>>(MW1, 1088, 1024, MW1tH, MW1tL);
    wconv_kernel<<<dim3((tot + 255) / 256), dim3(256), 0, stream>>>(OW1, 1088, 1024, OW1tH, nullptr);
    tot = 1024 * 1024;
    wconv_kernel<<<dim3((tot + 255) / 256), dim3(256), 0, stream>>>(MW2, 1024, 1024, MW2tH, MW2tL);
    wconv_kernel<<<dim3((tot + 255) / 256), dim3(256), 0, stream>>>(OW2, 1024, 1024, OW2tH, nullptr);
    wconv_kernel<<<dim3((tot + 255) / 256), dim3(256), 0, stream>>>(MW3, 1024, 1024, MW3tH, MW3tL);
    init_summary_kernel<<<dim3(32768), dim3(256), 0, stream>>>(agg, sumH, sacc);
    tow_conv_all_kernel<<<dim3(32768), dim3(256), 0, stream>>>(towers, towAllH);
  }

  const dim3 G(32, 8), B256(256);   // 256x128 tiles over 8192x1024 -> 256 blocks
  for (int k = 0; k < 16; ++k) {
    const _Float16* towH = towAllH + (size_t)k * 8192 * 64;

    // K1m: x=[sum|tow] @ MW1^T -> m1 (2-MFMA: weight-lo kept)
    gemm_split_kernel<<<G, B256, 0, stream>>>(sumH, 1024, towH, 64,
                                              1024, 1088, MW1tH, MW1tL, Mb1, m1H, 1024);
    // K1h: x=[sum|tow] @ OW1^T -> h1 (fp16)
    gemm_h_kernel<<<G, B256, 0, stream>>>(sumH, 1024, towH, 64, 1024, 1088,
                                          OW1tH, Ob1, h1, 1024, nullptr, nullptr);
    // K2m: m1 @ MW2^T -> m2 (2-MFMA)
    gemm_split_kernel<<<G, B256, 0, stream>>>(m1H, 1024, m1H, 1024,
                                              1024, 1024, MW2tH, MW2tL, Mb2, m2H, 1024);
    // K2h: h1 @ OW2^T -> fused relu+dot(OW3) into sacc (fp16)
    gemm_h_kernel<<<G, B256, 0, stream>>>(h1, 1024, h1, 1024, 1024, 1024,
                                          OW2tH, Ob2, nullptr, 1024, OW3, sacc);
    // K3: m2 @ MW3^T -> summary (2-MFMA; in-place: K1m/K1h already consumed it)
    gemm_split_kernel<<<G, B256, 0, stream>>>(m2H, 1024, m2H, 1024,
                                              1024, 1024, MW3tH, MW3tL, Mb3, sumH, 1024);
    // pred + product accumulate + re-zero sacc
    pred_final_kernel<<<dim3(32), dim3(256), 0, stream>>>(sacc, Ob3, out, k);
  }
}

// Round 8
// 2452.856 us; speedup vs baseline: 1.2225x; 1.2225x over previous
//
#include <hip/hip_runtime.h>
#include <cstdint>
#include <cstddef>

// BottomUpNet: N=8192 rows independent; K=16 sequential steps.
// R19: FLOP cut + dispatch fusion. R11-R18 ledger: six schedule families
// (1ph/2ph/small-tile/counted-vmcnt/phase-split/read-ahead) all at 44-53us,
// MfmaUtil 30+-3% — every variant sits at ~3.1x its MFMA floor; schedule
// knobs exhausted, so cut the FLOPs:
//  (1) m-chain 2-MFMA (weight hi/lo) -> 1 MFMA (pure fp16 weights).
//      Error budget: activations already fp16 (5e-4 rel) everywhere and
//      absmax=1.192e-7 is activation-dominated (R10->R11 cut a MFMA with
//      bit-identical absmax). Adding fp16 weight error (~same scale)
//      predicts absmax 1.5-2.5e-7 vs threshold 3.77e-7.
//      REVERT PLAN if absmax fails: restore weight-lo (BL + second MFMA)
//      for the three M-layers, keep the K1 fusion below.
//  (2) K1m+K1h fused: W1cat=[MW1t;OW1t] (2048x1088), one dispatch
//      grid(32,16) -> mh1[8192][2048] (m1=cols 0..1023, h1=1024..2047,
//      consumed with ldA=2048). A=[sum|tow] staged once, 5->4 GEMMs/step.
// Kernel structure = R18's 4-buffer read-ahead h-kernel (equal-fastest).
// Predicted: step ~125us -> total ~2100us; absmax 1.5-2.5e-7.

typedef _Float16 f16x8 __attribute__((ext_vector_type(8)));
typedef float f32x16 __attribute__((ext_vector_type(16)));

#define MF(d, a, b) d = __builtin_amdgcn_mfma_f32_32x32x16_f16(a, b, d, 0, 0, 0)
#define CFENCE() asm volatile("" ::: "memory")

__device__ __forceinline__ void gload16(const void* g, void* l) {
  // async global->LDS, 16B/lane, LDS dest = wave-uniform base + lane*16
  __builtin_amdgcn_global_load_lds(
      (__attribute__((address_space(1))) void*)const_cast<void*>(g),
      (__attribute__((address_space(3))) void*)l,
      16, 0, 0);
}

// ---- fp16 GEMM: C = relu(A@B^T + bias) fp16 out,
// or fused-pred mode (sacc != null): sacc[row] += sum_col relu(.)*w3[col]
// Tile 256x128, BK=32, 4 waves (128x64 each), 4-buffer read-ahead pipeline.
__global__ __launch_bounds__(256, 1)
void gemm_h_kernel(const _Float16* __restrict__ A0, int ldA0,
                   const _Float16* __restrict__ A1, int ldA1,
                   int kcut, int Ktot,
                   const _Float16* __restrict__ B,
                   const float* __restrict__ bias,
                   _Float16* __restrict__ C, int ldC,
                   const float* __restrict__ w3, float* __restrict__ sacc)
{
  __shared__ _Float16 sA[4][256 * 32];   // 64 KB
  __shared__ _Float16 sB[4][128 * 32];   // 32 KB

  const int lane = threadIdx.x & 63;
  const int wave = threadIdx.x >> 6;
  const int wm = (wave >> 1) * 128, wn = (wave & 1) * 64;
  const int mBase = blockIdx.x * 256, nBase = blockIdx.y * 128;

  // paired-row staging layout (R13-verified): chunk = 16 logical rows
  const int lr  = 2 * (lane >> 3) + ((lane >> 2) & 1);
  const int lcs = (((lane & 3) ^ ((lane >> 3) & 3)) * 8);

  const int l31 = lane & 31, l5 = lane >> 5;
  const int rowoff = (l31 >> 1) * 64 + (l31 & 1) * 32;
  const int fswz = (l31 >> 1) & 3;
  const int ko0 = (l5 ^ fswz) * 8;
  const int ko1 = ((2 + l5) ^ fswz) * 8;

  const _Float16 *aS0[4], *aS1[4], *bS[2];
#pragma unroll
  for (int q = 0; q < 4; ++q) {
    const int row = mBase + (wave + q * 4) * 16 + lr;
    aS0[q] = A0 + (size_t)row * ldA0 + lcs;
    aS1[q] = A1 + (size_t)row * ldA1 + lcs;
  }
#pragma unroll
  for (int q = 0; q < 2; ++q) {
    const int row = nBase + (wave + q * 4) * 16 + lr;
    bS[q] = B + (size_t)row * Ktot + lcs;
  }

  f32x16 acc[4][2];
#pragma unroll
  for (int i = 0; i < 4; ++i)
#pragma unroll
    for (int j = 0; j < 2; ++j) acc[i][j] = (f32x16)0.0f;

  _Float16 *uA0 = &sA[0][0], *uA1 = &sA[1][0], *uA2 = &sA[2][0], *uA3 = &sA[3][0];
  _Float16 *uB0 = &sB[0][0], *uB1 = &sB[1][0], *uB2 = &sB[2][0], *uB3 = &sB[3][0];

  auto STAGE = [&](_Float16* dA, _Float16* dB, int kt) {   // 6 loads
    const bool lo = kt < kcut;
    const int kl = lo ? kt : kt - kcut;
#pragma unroll
    for (int q = 0; q < 4; ++q)
      gload16((lo ? aS0[q] : aS1[q]) + kl, dA + (wave + q * 4) * 512);
#pragma unroll
    for (int q = 0; q < 2; ++q)
      gload16(bS[q] + kt, dB + (wave + q * 4) * 512);
  };

  auto DSREAD = [&](const _Float16* pA, const _Float16* pB,
                    f16x8 (&a)[4][2], f16x8 (&b)[2][2]) {  // 12 b128
#pragma unroll
    for (int i = 0; i < 4; ++i) {
      const int base = (wm + i * 32) * 32 + rowoff;
      a[i][0] = *(const f16x8*)(pA + base + ko0);
      a[i][1] = *(const f16x8*)(pA + base + ko1);
    }
#pragma unroll
    for (int j = 0; j < 2; ++j) {
      const int base = (wn + j * 32) * 32 + rowoff;
      b[j][0] = *(const f16x8*)(pB + base + ko0);
      b[j][1] = *(const f16x8*)(pB + base + ko1);
    }
  };

  auto MFMACL = [&](f16x8 (&a)[4][2], f16x8 (&b)[2][2]) {  // 16 MFMA
#pragma unroll
    for (int kh = 0; kh < 2; ++kh)
#pragma unroll
      for (int i = 0; i < 4; ++i)
#pragma unroll
        for (int j = 0; j < 2; ++j) MF(acc[i][j], a[i][kh], b[j][kh]);
  };

  f16x8 aX[4][2], bX[2][2];
  f16x8 aY[4][2], bY[2][2];

  const int NT = Ktot >> 5;                // 32 or 34 (even)
  STAGE(uA0, uB0, 0);
  STAGE(uA1, uB1, 32);
  asm volatile("s_waitcnt vmcnt(6)" ::: "memory");  // tile0 landed
  __builtin_amdgcn_s_barrier();
  CFENCE();
  DSREAD(uA0, uB0, aX, bX);

  for (int t = 0; t < NT; t += 2) {
    // ---- even: compute X(t); read-ahead Y(t+1); stage(t+2) -> u2
    {
      const bool s2 = (t + 2) < NT;
      if (s2) STAGE(uA2, uB2, (t + 2) * 32);
      if (s2) asm volatile("s_waitcnt vmcnt(6)" ::: "memory");
      else    asm volatile("s_waitcnt vmcnt(0)" ::: "memory");
      __builtin_amdgcn_s_barrier();
      CFENCE();
      asm volatile("s_waitcnt lgkmcnt(0)" ::: "memory");  // X-frags ready (free)
      DSREAD(uA1, uB1, aY, bY);                           // t+1 always < NT
      __builtin_amdgcn_sched_barrier(0);
      __builtin_amdgcn_s_setprio(1);
      MFMACL(aX, bX);
      __builtin_amdgcn_s_setprio(0);
    }
    // ---- odd: compute Y(t+1); read-ahead X(t+2); stage(t+3) -> u3
    {
      const bool s2 = (t + 3) < NT;
      const bool r2 = (t + 2) < NT;
      if (s2) STAGE(uA3, uB3, (t + 3) * 32);
      if (s2)      asm volatile("s_waitcnt vmcnt(6)" ::: "memory");
      else if (r2) asm volatile("s_waitcnt vmcnt(0)" ::: "memory");
      __builtin_amdgcn_s_barrier();
      CFENCE();
      asm volatile("s_waitcnt lgkmcnt(0)" ::: "memory");  // Y-frags ready
      if (r2) DSREAD(uA2, uB2, aX, bX);
      __builtin_amdgcn_sched_barrier(0);
      __builtin_amdgcn_s_setprio(1);
      MFMACL(aY, bY);
      __builtin_amdgcn_s_setprio(0);
    }
    { _Float16* tp;
      tp = uA0; uA0 = uA2; uA2 = tp;  tp = uA1; uA1 = uA3; uA3 = tp;
      tp = uB0; uB0 = uB2; uB2 = tp;  tp = uB1; uB1 = uB3; uB3 = tp; }
  }

  float bv[2], w3v[2];
#pragma unroll
  for (int j = 0; j < 2; ++j) {
    const int col = nBase + wn + j * 32 + l31;
    bv[j] = bias[col];
    w3v[j] = sacc ? w3[col] : 0.0f;
  }

  if (sacc) {
    // fused pred partial: one value per C/D row, reduced over the 32 col-lanes
#pragma unroll
    for (int i = 0; i < 4; ++i)
#pragma unroll
      for (int r = 0; r < 16; ++r) {
        float pr = 0.0f;
#pragma unroll
        for (int j = 0; j < 2; ++j)
          pr += fmaxf(acc[i][j][r] + bv[j], 0.0f) * w3v[j];
        pr += __shfl_xor(pr, 1);
        pr += __shfl_xor(pr, 2);
        pr += __shfl_xor(pr, 4);
        pr += __shfl_xor(pr, 8);
        pr += __shfl_xor(pr, 16);
        if (l31 == 0)
          atomicAdd(&sacc[mBase + wm + i * 32 + (r & 3) + 8 * (r >> 2) + 4 * l5], pr);
      }
  } else {
#pragma unroll
    for (int i = 0; i < 4; ++i)
#pragma unroll
      for (int j = 0; j < 2; ++j)
#pragma unroll
        for (int r = 0; r < 16; ++r) {
          const int row = mBase + wm + i * 32 + (r & 3) + 8 * (r >> 2) + 4 * l5;
          const int col = nBase + wn + j * 32 + l31;
          float v = fmaxf(acc[i][j][r] + bv[j], 0.0f);
          C[(size_t)row * ldC + col] = (_Float16)v;
        }
  }
}

// W (K x N fp32, row-major) -> out (N x K fp16), i.e. transposed
__global__ void wconv_kernel(const float* __restrict__ W, int K, int N,
                             _Float16* __restrict__ oH) {
  int idx = blockIdx.x * 256 + threadIdx.x;   // idx = n*K + k (output-coalesced)
  if (idx >= K * N) return;
  int n = idx / K, k = idx - n * K;
  oH[idx] = (_Float16)W[(size_t)k * N + n];
}

__global__ void init_summary_kernel(const float* __restrict__ agg,
                                    _Float16* __restrict__ sH,
                                    float* __restrict__ sacc) {
  int idx = blockIdx.x * 256 + threadIdx.x;   // 8192*1024
  sH[idx] = (_Float16)agg[idx & 1023];
  if (idx < 8192) sacc[idx] = 0.0f;
}

// bias concat: b1cat = [Mb1 | Ob1] (2048 floats)
__global__ void biascat_kernel(const float* __restrict__ b0,
                               const float* __restrict__ b1,
                               float* __restrict__ o) {
  int idx = blockIdx.x * 256 + threadIdx.x;   // 2048
  o[idx] = (idx < 1024) ? b0[idx] : b1[idx - 1024];
}

// towers [n][k][f] fp32 -> towAll [k][n][f] fp16 (all 16 slices)
__global__ void tow_conv_all_kernel(const float* __restrict__ towers,
                                    _Float16* __restrict__ oH) {
  size_t idx = (size_t)blockIdx.x * 256 + threadIdx.x;  // (k*8192+n)*64+f
  int f = idx & 63;
  int n = (int)((idx >> 6) & 8191);
  int k = (int)(idx >> 19);
  oH[idx] = (_Float16)towers[((size_t)n * 16 + k) * 64 + f];
}

// pred = sigmoid(sacc + Ob3); out *= pred; re-zero sacc for next step
__global__ void pred_final_kernel(float* __restrict__ sacc, const float* __restrict__ b3,
                                  float* __restrict__ out, int step) {
  int row = blockIdx.x * 256 + threadIdx.x;   // 8192
  float p = 1.0f / (1.0f + expf(-(sacc[row] + b3[0])));
  out[row] = (step == 0) ? p : out[row] * p;
  sacc[row] = 0.0f;
}

extern "C" void kernel_launch(void* const* d_in, const int* in_sizes, int n_in,
                              void* d_out, int out_size, void* d_ws, size_t ws_size,
                              hipStream_t stream) {
  const float* towers = (const float*)d_in[0];
  const float* agg    = (const float*)d_in[1];
  const float* MW1 = (const float*)d_in[2];
  const float* Mb1 = (const float*)d_in[3];
  const float* MW2 = (const float*)d_in[4];
  const float* Mb2 = (const float*)d_in[5];
  const float* MW3 = (const float*)d_in[6];
  const float* Mb3 = (const float*)d_in[7];
  const float* OW1 = (const float*)d_in[8];
  const float* Ob1 = (const float*)d_in[9];
  const float* OW2 = (const float*)d_in[10];
  const float* Ob2 = (const float*)d_in[11];
  const float* OW3 = (const float*)d_in[12];
  const float* Ob3 = (const float*)d_in[13];
  float* out = (float*)d_out;

  // ws layout (~95 MiB)
  _Float16* p = (_Float16*)d_ws;
  _Float16* W1catH = p; p += (size_t)2048 * 1088;   // [MW1t rows 0..1023 | OW1t rows 1024..2047]
  _Float16* MW2tH  = p; p += (size_t)1024 * 1024;
  _Float16* OW2tH  = p; p += (size_t)1024 * 1024;
  _Float16* MW3tH  = p; p += (size_t)1024 * 1024;
  _Float16* sumH   = p; p += (size_t)8192 * 1024;
  _Float16* mh1    = p; p += (size_t)8192 * 2048;   // m1 = cols 0..1023, h1 = cols 1024..2047
  _Float16* m2H    = p; p += (size_t)8192 * 1024;
  _Float16* towAllH = p; p += (size_t)16 * 8192 * 64;
  float* sacc  = (float*)p;
  float* b1cat = sacc + 8192;

  // per-call setup: transpose weights (fp16), concat W1/b1, towers, summary
  {
    int tot = 1088 * 1024;
    wconv_kernel<<<dim3((tot + 255) / 256), dim3(256), 0, stream>>>(MW1, 1088, 1024, W1catH);
    wconv_kernel<<<dim3((tot + 255) / 256), dim3(256), 0, stream>>>(OW1, 1088, 1024, W1catH + (size_t)1024 * 1088);
    tot = 1024 * 1024;
    wconv_kernel<<<dim3((tot + 255) / 256), dim3(256), 0, stream>>>(MW2, 1024, 1024, MW2tH);
    wconv_kernel<<<dim3((tot + 255) / 256), dim3(256), 0, stream>>>(OW2, 1024, 1024, OW2tH);
    wconv_kernel<<<dim3((tot + 255) / 256), dim3(256), 0, stream>>>(MW3, 1024, 1024, MW3tH);
    biascat_kernel<<<dim3(8), dim3(256), 0, stream>>>(Mb1, Ob1, b1cat);
    init_summary_kernel<<<dim3(32768), dim3(256), 0, stream>>>(agg, sumH, sacc);
    tow_conv_all_kernel<<<dim3(32768), dim3(256), 0, stream>>>(towers, towAllH);
  }

  const dim3 G1(32, 16), G(32, 8), B256(256);
  for (int k = 0; k < 16; ++k) {
    const _Float16* towH = towAllH + (size_t)k * 8192 * 64;

    // K1 (fused K1m+K1h): x=[sum|tow] @ W1cat^T -> mh1 (m1|h1), N=2048
    gemm_h_kernel<<<G1, B256, 0, stream>>>(sumH, 1024, towH, 64, 1024, 1088,
                                           W1catH, b1cat, mh1, 2048, nullptr, nullptr);
    // K2m: m1 @ MW2^T -> m2
    gemm_h_kernel<<<G, B256, 0, stream>>>(mh1, 2048, mh1, 2048, 1024, 1024,
                                          MW2tH, Mb2, m2H, 1024, nullptr, nullptr);
    // K2h: h1 @ OW2^T -> fused relu+dot(OW3) into sacc
    gemm_h_kernel<<<G, B256, 0, stream>>>(mh1 + 1024, 2048, mh1 + 1024, 2048, 1024, 1024,
                                          OW2tH, Ob2, nullptr, 1024, OW3, sacc);
    // K3: m2 @ MW3^T -> summary
    gemm_h_kernel<<<G, B256, 0, stream>>>(m2H, 1024, m2H, 1024, 1024, 1024,
                                          MW3tH, Mb3, sumH, 1024, nullptr, nullptr);
    // pred + product accumulate + re-zero sacc
    pred_final_kernel<<<dim3(32), dim3(256), 0, stream>>>(sacc, Ob3, out, k);
  }
}